// Round 10
// baseline (664.231 us; speedup 1.0000x reference)
//
#include <hip/hip_runtime.h>

#define N_NODES 50000
#define N_EDGES 600000
#define HC 256
#define NH 8
#define AGG_BLOCKS 2048
#define AGG_WAVES (AGG_BLOCKS * 4)

typedef short s8v __attribute__((ext_vector_type(8)));
typedef float f4v __attribute__((ext_vector_type(4)));
typedef _Float16 h4v __attribute__((ext_vector_type(4)));
typedef _Float16 h8v __attribute__((ext_vector_type(8)));
typedef __attribute__((address_space(1))) const unsigned int as1_cu32;
typedef __attribute__((address_space(3))) unsigned int as3_u32;

__device__ inline ushort f2bf(float f) {
  unsigned u = __float_as_uint(f);
  unsigned r = u + 0x7FFF + ((u >> 16) & 1);  // RNE
  return (ushort)(r >> 16);
}

// ---------------------------------------------------------------- CSR build
__global__ void k_init_cnt(int* __restrict__ cnt) {
  int i = blockIdx.x * 256 + threadIdx.x;
  if (i < N_NODES) cnt[i] = 1;  // self-loop
}

__global__ void k_count(const int* __restrict__ dstE, int* __restrict__ cnt) {
  int e = blockIdx.x * 256 + threadIdx.x;
  if (e < N_EDGES) atomicAdd(&cnt[dstE[e]], 1);
}

__global__ void k_scan_bsum(const int* __restrict__ cnt, int* __restrict__ bsum) {
  __shared__ int sd[256];
  int i = blockIdx.x * 256 + threadIdx.x;
  sd[threadIdx.x] = (i < N_NODES) ? cnt[i] : 0;
  __syncthreads();
  for (int o = 128; o > 0; o >>= 1) {
    if (threadIdx.x < o) sd[threadIdx.x] += sd[threadIdx.x + o];
    __syncthreads();
  }
  if (threadIdx.x == 0) bsum[blockIdx.x] = sd[0];
}

__global__ void k_scan_offsets(int* __restrict__ bsum, int nb) {
  __shared__ int s[256];
  int t = threadIdx.x;
  int v = (t < nb) ? bsum[t] : 0;
  s[t] = v; __syncthreads();
  for (int o = 1; o < 256; o <<= 1) {
    int x = (t >= o) ? s[t - o] : 0;
    __syncthreads();
    s[t] += x;
    __syncthreads();
  }
  if (t < nb) bsum[t] = s[t] - v;  // exclusive
}

__global__ void k_scan_write(const int* __restrict__ cnt, const int* __restrict__ bsum,
                             int* __restrict__ rowptr, int* __restrict__ fillptr) {
  __shared__ int s[256];
  int t = threadIdx.x;
  int i = blockIdx.x * 256 + t;
  int v = (i < N_NODES) ? cnt[i] : 0;
  s[t] = v; __syncthreads();
  for (int o = 1; o < 256; o <<= 1) {
    int x = (t >= o) ? s[t - o] : 0;
    __syncthreads();
    s[t] += x;
    __syncthreads();
  }
  int excl = s[t] - v + bsum[blockIdx.x];
  if (i < N_NODES) {
    rowptr[i] = excl;
    fillptr[i] = excl;
    if (i == N_NODES - 1) rowptr[N_NODES] = excl + v;
  }
}

__global__ void k_fill(const int* __restrict__ srcE, const int* __restrict__ dstE,
                       int* __restrict__ fillptr, int* __restrict__ srcs) {
  int i = blockIdx.x * 256 + threadIdx.x;
  if (i < N_NODES) {
    int pos = atomicAdd(&fillptr[i], 1);
    srcs[pos] = i;                       // self-loop
  } else if (i < N_NODES + N_EDGES) {
    int e = i - N_NODES;
    int pos = atomicAdd(&fillptr[dstE[e]], 1);
    srcs[pos] = srcE[e];
  }
}

// ---------------------------------------------------------------- fp32 -> bf16 convert (x)
__global__ void k_cvt_x(const float* __restrict__ X, ushort* __restrict__ Xb) {
  size_t i = ((size_t)blockIdx.x * 256 + threadIdx.x) * 4;
  float4 x4 = *(const float4*)&X[i];
  ushort4 o;
  o.x = f2bf(x4.x); o.y = f2bf(x4.y); o.z = f2bf(x4.z); o.w = f2bf(x4.w);
  *(ushort4*)&Xb[i] = o;
}

// ---------------------------------------------------------------- all weight prep in ONE kernel
// blocks 0-31: gat1_W -> WtP[0:256]; 32-63: res_W -> WtP[256:512];
// 64-127: gat2_W -> Wt2; 128-191: gat3_W -> Wt3; 192-319: pack head -> Wth.
__global__ void k_prep(const float* __restrict__ gW0, const float* __restrict__ resW,
                       const float* __restrict__ gW1, const float* __restrict__ gW2,
                       const float* __restrict__ muW, const float* __restrict__ lvW,
                       const float* __restrict__ auxW,
                       ushort* __restrict__ WtP, ushort* __restrict__ Wt2,
                       ushort* __restrict__ Wt3, ushort* __restrict__ Wth) {
  __shared__ ushort s[32][33];
  int id = blockIdx.x;
  int t = threadIdx.x;
  if (id < 64) {                       // K=128 transposes into WtP
    const float* W = (id < 32) ? gW0 : resW;
    ushort* Wt = (id < 32) ? WtP : (WtP + 256 * 128);
    int a = id & 31;
    int bx = a & 3, by = a >> 2;       // grid (4,8)
    int tx = t & 31, ty = t >> 5;
    int k0 = bx * 32, n0 = by * 32;
    for (int j = 0; j < 32; j += 8)
      s[ty + j][tx] = f2bf(W[(size_t)(k0 + ty + j) * 256 + n0 + tx]);
    __syncthreads();
    for (int j = 0; j < 32; j += 8)
      Wt[(size_t)(n0 + ty + j) * 128 + k0 + tx] = s[tx][ty + j];
  } else if (id < 192) {               // K=256 transposes
    const float* W = (id < 128) ? gW1 : gW2;
    ushort* Wt = (id < 128) ? Wt2 : Wt3;
    int a = (id - 64) & 63;
    int bx = a & 7, by = a >> 3;       // grid (8,8)
    int tx = t & 31, ty = t >> 5;
    int k0 = bx * 32, n0 = by * 32;
    for (int j = 0; j < 32; j += 8)
      s[ty + j][tx] = f2bf(W[(size_t)(k0 + ty + j) * 256 + n0 + tx]);
    __syncthreads();
    for (int j = 0; j < 32; j += 8)
      Wt[(size_t)(n0 + ty + j) * 256 + k0 + tx] = s[tx][ty + j];
  } else {                             // pack [muW|lvW|auxW|0] -> Wth[128][256]
    int n = id - 192;                  // 0..127
    int k = t;                         // 0..255
    float v = 0.f;
    if (n < 32) v = muW[k * 32 + n];
    else if (n < 64) v = lvW[k * 32 + (n - 32)];
    else if (n < 94) v = auxW[k * 30 + (n - 64)];
    Wth[n * 256 + k] = f2bf(v);
  }
}

// ---------------------------------------------------------------- bf16 MFMA GEMM, 128x64 tile (layer 1)
// bias_off: cols < bias_off get 0, cols >= bias_off get bias[col - bias_off].
// Fused att epilogue: 64-col tile = 2 complete heads, one head per wave.
template <typename OutT>
__launch_bounds__(256)
__global__ void k_gemm_bf16(const ushort* __restrict__ A, const ushort* __restrict__ Wt,
                            const float* __restrict__ bias, int bias_off, OutT* __restrict__ Out,
                            int M, int K, int ldc,
                            const float* __restrict__ att_asrc, const float* __restrict__ att_adst,
                            float* __restrict__ att_as, float* __restrict__ att_ad) {
  __shared__ __align__(16) ushort As[16 * 512];  // 16 KB (A: 128 rows)
  __shared__ __align__(16) ushort Bs[8 * 512];   //  8 KB (B:  64 rows)
  int t = threadIdx.x, w = t >> 6, L = t & 63;
  int bm = blockIdx.x * 128, bn = blockIdx.y * 64;
  int lrow = L & 15, lcol = (L >> 4) * 8;

  const ushort* ga[4];
  const ushort* gb[2];
#pragma unroll
  for (int u = 0; u < 4; u++) {
    int i = w * 4 + u;
    int mt = i >> 1, ks = i & 1;
    int arow = bm + mt * 16 + lrow;
    if (arow >= M) arow = M - 1;
    ga[u] = A + (size_t)arow * K + ks * 32 + lcol;
  }
#pragma unroll
  for (int u = 0; u < 2; u++) {
    int i = w * 2 + u;
    int mt = i >> 1, ks = i & 1;
    int brow = bn + mt * 16 + lrow;
    gb[u] = Wt + (size_t)brow * K + ks * 32 + lcol;
  }

  f4v acc[4][2];
  f4v zero = {0.f, 0.f, 0.f, 0.f};
#pragma unroll
  for (int mi = 0; mi < 4; mi++)
#pragma unroll
    for (int ni = 0; ni < 2; ni++) acc[mi][ni] = zero;

  int wm = (w >> 1) * 4;
  int wn = (w & 1) * 2;

  int nk = K >> 6;
  for (int kt = 0; kt < nk; kt++) {
#pragma unroll
    for (int u = 0; u < 4; u++) {
      int i = w * 4 + u;
      __builtin_amdgcn_global_load_lds((as1_cu32*)ga[u], (as3_u32*)&As[i * 512], 16, 0, 0);
      ga[u] += 64;
    }
#pragma unroll
    for (int u = 0; u < 2; u++) {
      int i = w * 2 + u;
      __builtin_amdgcn_global_load_lds((as1_cu32*)gb[u], (as3_u32*)&Bs[i * 512], 16, 0, 0);
      gb[u] += 64;
    }
    __syncthreads();
#pragma unroll
    for (int ks = 0; ks < 2; ks++) {
      s8v af[4], bf[2];
#pragma unroll
      for (int mi = 0; mi < 4; mi++)
        af[mi] = *(const s8v*)&As[(((wm + mi) * 2 + ks) * 64 + L) * 8];
#pragma unroll
      for (int ni = 0; ni < 2; ni++)
        bf[ni] = *(const s8v*)&Bs[(((wn + ni) * 2 + ks) * 64 + L) * 8];
#pragma unroll
      for (int mi = 0; mi < 4; mi++)
#pragma unroll
        for (int ni = 0; ni < 2; ni++)
          acc[mi][ni] = __builtin_amdgcn_mfma_f32_16x16x32_bf16(af[mi], bf[ni], acc[mi][ni], 0, 0, 0);
    }
    __syncthreads();
  }
#pragma unroll
  for (int ni = 0; ni < 2; ni++) {
    int col = bn + (wn + ni) * 16 + (L & 15);
    float bb = (bias && col >= bias_off) ? bias[col - bias_off] : 0.f;
#pragma unroll
    for (int mi = 0; mi < 4; mi++) {
      int rbase = bm + (wm + mi) * 16 + (L >> 4) * 4;
#pragma unroll
      for (int i = 0; i < 4; i++) {
        int r = rbase + i;
        if (r < M) Out[(size_t)r * ldc + col] = (OutT)(acc[mi][ni][i] + bb);
      }
    }
  }
  // ---- fused attention logits (one complete head per wave) ----
  if (att_as && bn < 256) {
    int hb = ((unsigned)(bn + wn * 16)) >> 5;   // wave's head
    int cl = L & 15;
    float sa0 = att_asrc[hb * 32 + cl],  sa1 = att_asrc[hb * 32 + 16 + cl];
    float da0 = att_adst[hb * 32 + cl],  da1 = att_adst[hb * 32 + 16 + cl];
#pragma unroll
    for (int mi = 0; mi < 4; mi++) {
#pragma unroll
      for (int i = 0; i < 4; i++) {
        float vs = acc[mi][0][i] * sa0 + acc[mi][1][i] * sa1;
        float vd = acc[mi][0][i] * da0 + acc[mi][1][i] * da1;
        vs += __shfl_xor(vs, 1); vd += __shfl_xor(vd, 1);
        vs += __shfl_xor(vs, 2); vd += __shfl_xor(vd, 2);
        vs += __shfl_xor(vs, 4); vd += __shfl_xor(vd, 4);
        vs += __shfl_xor(vs, 8); vd += __shfl_xor(vd, 8);
        int r = bm + (wm + mi) * 16 + (L >> 4) * 4 + i;
        if (cl == 0 && r < M) {
          att_as[r * NH + hb] = vs;
          att_ad[r * NH + hb] = vd;
        }
      }
    }
  }
}

// ---------------------------------------------------------------- GEMM with BN+ReLU fused A-staging (layers 2,3)
// A = X1 (fp16 agg output); BN scale/shift computed inline from stats/g/b;
// A staged via regs -> ds_write to the SAME LDS layout gld_lds produces.
// B via global_load_lds. K=256, M=N_NODES, ldc=256, tile 128x64.
__launch_bounds__(256)
__global__ void k_gemm_bn(const _Float16* __restrict__ A, const ushort* __restrict__ Wt,
                          const float* __restrict__ stats, const float* __restrict__ g,
                          const float* __restrict__ b, _Float16* __restrict__ Out,
                          const float* __restrict__ att_asrc, const float* __restrict__ att_adst,
                          float* __restrict__ att_as, float* __restrict__ att_ad) {
  __shared__ __align__(16) ushort As[16 * 512];  // 16 KB
  __shared__ __align__(16) ushort Bs[8 * 512];   //  8 KB
  const int K = 256, M = N_NODES, ldc = 256;
  const float invN = 1.f / (float)N_NODES;
  int t = threadIdx.x, w = t >> 6, L = t & 63;
  int bm = blockIdx.x * 128, bn = blockIdx.y * 64;
  int lrow = L & 15, lcol = (L >> 4) * 8;

  int arow[4];
  const ushort* gb[2];
#pragma unroll
  for (int u = 0; u < 4; u++) {
    int i = w * 4 + u;
    int mt = i >> 1;
    int r = bm + mt * 16 + lrow;
    arow[u] = (r >= M) ? (M - 1) : r;
  }
#pragma unroll
  for (int u = 0; u < 2; u++) {
    int i = w * 2 + u;
    int mt = i >> 1, ks = i & 1;
    gb[u] = Wt + (size_t)(bn + mt * 16 + lrow) * K + ks * 32 + lcol;
  }

  f4v acc[4][2];
  f4v zero = {0.f, 0.f, 0.f, 0.f};
#pragma unroll
  for (int mi = 0; mi < 4; mi++)
#pragma unroll
    for (int ni = 0; ni < 2; ni++) acc[mi][ni] = zero;

  int wm = (w >> 1) * 4;
  int wn = (w & 1) * 2;

  for (int kt = 0; kt < 4; kt++) {
#pragma unroll
    for (int u = 0; u < 2; u++) {
      int i = w * 2 + u;
      __builtin_amdgcn_global_load_lds((as1_cu32*)gb[u], (as3_u32*)&Bs[i * 512], 16, 0, 0);
      gb[u] += 64;
    }
    // A: load fp16 -> BN scale/shift + relu -> bf16 -> ds_write (same slot as gld_lds)
#pragma unroll
    for (int u = 0; u < 4; u++) {
      int i = w * 4 + u;
      int ks = i & 1;
      int c0 = kt * 64 + ks * 32 + lcol;
      h8v a8 = *(const h8v*)&A[(size_t)arow[u] * 256 + c0];
      ushort o8[8];
#pragma unroll
      for (int q2 = 0; q2 < 2; q2++) {
        float4 s4 = *(const float4*)&stats[c0 + q2 * 4];
        float4 q4 = *(const float4*)&stats[256 + c0 + q2 * 4];
        float4 g4 = *(const float4*)&g[c0 + q2 * 4];
        float4 b4 = *(const float4*)&b[c0 + q2 * 4];
        float sm[4] = {s4.x, s4.y, s4.z, s4.w};
        float qm[4] = {q4.x, q4.y, q4.z, q4.w};
        float gm[4] = {g4.x, g4.y, g4.z, g4.w};
        float bm_[4] = {b4.x, b4.y, b4.z, b4.w};
#pragma unroll
        for (int j = 0; j < 4; j++) {
          float m = sm[j] * invN;
          float rs = rsqrtf(qm[j] * invN - m * m + 1e-5f) * gm[j];
          float v = ((float)a8[q2 * 4 + j] - m) * rs + bm_[j];
          v = v > 0.f ? v : 0.f;
          o8[q2 * 4 + j] = f2bf(v);
        }
      }
      *(uint4*)&As[(size_t)i * 512 + L * 8] = *(const uint4*)o8;
    }
    __syncthreads();
#pragma unroll
    for (int ks = 0; ks < 2; ks++) {
      s8v af[4], bf[2];
#pragma unroll
      for (int mi = 0; mi < 4; mi++)
        af[mi] = *(const s8v*)&As[(((wm + mi) * 2 + ks) * 64 + L) * 8];
#pragma unroll
      for (int ni = 0; ni < 2; ni++)
        bf[ni] = *(const s8v*)&Bs[(((wn + ni) * 2 + ks) * 64 + L) * 8];
#pragma unroll
      for (int mi = 0; mi < 4; mi++)
#pragma unroll
        for (int ni = 0; ni < 2; ni++)
          acc[mi][ni] = __builtin_amdgcn_mfma_f32_16x16x32_bf16(af[mi], bf[ni], acc[mi][ni], 0, 0, 0);
    }
    __syncthreads();
  }
#pragma unroll
  for (int ni = 0; ni < 2; ni++) {
    int col = bn + (wn + ni) * 16 + (L & 15);
#pragma unroll
    for (int mi = 0; mi < 4; mi++) {
      int rbase = bm + (wm + mi) * 16 + (L >> 4) * 4;
#pragma unroll
      for (int i = 0; i < 4; i++) {
        int r = rbase + i;
        if (r < M) Out[(size_t)r * ldc + col] = (_Float16)(acc[mi][ni][i]);
      }
    }
  }
  // ---- fused attention logits (one complete head per wave) ----
  {
    int hb = ((unsigned)(bn + wn * 16)) >> 5;   // wave's head
    int cl = L & 15;
    float sa0 = att_asrc[hb * 32 + cl],  sa1 = att_asrc[hb * 32 + 16 + cl];
    float da0 = att_adst[hb * 32 + cl],  da1 = att_adst[hb * 32 + 16 + cl];
#pragma unroll
    for (int mi = 0; mi < 4; mi++) {
#pragma unroll
      for (int i = 0; i < 4; i++) {
        float vs = acc[mi][0][i] * sa0 + acc[mi][1][i] * sa1;
        float vd = acc[mi][0][i] * da0 + acc[mi][1][i] * da1;
        vs += __shfl_xor(vs, 1); vd += __shfl_xor(vd, 1);
        vs += __shfl_xor(vs, 2); vd += __shfl_xor(vd, 2);
        vs += __shfl_xor(vs, 4); vd += __shfl_xor(vd, 4);
        vs += __shfl_xor(vs, 8); vd += __shfl_xor(vd, 8);
        int r = bm + (wm + mi) * 16 + (L >> 4) * 4 + i;
        if (cl == 0 && r < M) {
          att_as[r * NH + hb] = vs;
          att_ad[r * NH + hb] = vd;
        }
      }
    }
  }
}

// ---------------------------------------------------------------- head GEMM + fused BN/resid A-staging + decode
// A = X1 (layer-3 agg out, fp16); resid = X0R+256 (ld 512).
__launch_bounds__(256)
__global__ void k_gemm_head(const _Float16* __restrict__ A, const _Float16* __restrict__ resid,
                            const float* __restrict__ stats, const float* __restrict__ g,
                            const float* __restrict__ b, const ushort* __restrict__ Wt,
                            const float* __restrict__ eps,
                            const float* __restrict__ mub, const float* __restrict__ lvb,
                            const float* __restrict__ auxb,
                            const float* __restrict__ decW, const float* __restrict__ decb,
                            float* __restrict__ out) {
  __shared__ __align__(16) ushort smem[16384];   // As | Bs during loop; fp16 tile after
  __shared__ float wsd[2048];                    // decW [32][64]
  __shared__ float shz[4][32];
  ushort* As = smem;
  ushort* Bs = smem + 8192;
  const float invN = 1.f / (float)N_NODES;
  int t = threadIdx.x, w = t >> 6, L = t & 63;
  int bm = blockIdx.x * 128;
  int lrow = L & 15, lcol = (L >> 4) * 8;
  const int K = 256;
  for (int i = t; i < 2048; i += 256) wsd[i] = decW[i];

  int arow[4];
  const ushort* gb[4];
#pragma unroll
  for (int u = 0; u < 4; u++) {
    int i = w * 4 + u;
    int mt = i >> 1, ks = i & 1;
    int r = bm + mt * 16 + lrow;
    arow[u] = (r >= N_NODES) ? (N_NODES - 1) : r;
    int brow = mt * 16 + lrow;                   // bn = 0, 128 rows of Wth
    gb[u] = Wt + (size_t)brow * K + ks * 32 + lcol;
  }
  f4v acc[4][4];
  f4v zero = {0.f, 0.f, 0.f, 0.f};
#pragma unroll
  for (int mi = 0; mi < 4; mi++)
#pragma unroll
    for (int ni = 0; ni < 4; ni++) acc[mi][ni] = zero;
  int wm = (w >> 1) * 4;
  int wn = (w & 1) * 4;
  for (int kt = 0; kt < 4; kt++) {
#pragma unroll
    for (int u = 0; u < 4; u++) {
      int i = w * 4 + u;
      __builtin_amdgcn_global_load_lds((as1_cu32*)gb[u], (as3_u32*)&Bs[i * 512], 16, 0, 0);
      gb[u] += 64;
    }
#pragma unroll
    for (int u = 0; u < 4; u++) {
      int i = w * 4 + u;
      int ks = i & 1;
      int c0 = kt * 64 + ks * 32 + lcol;
      h8v a8 = *(const h8v*)&A[(size_t)arow[u] * 256 + c0];
      h8v r8 = *(const h8v*)&resid[(size_t)arow[u] * 512 + c0];
      ushort o8[8];
#pragma unroll
      for (int q2 = 0; q2 < 2; q2++) {
        float4 s4 = *(const float4*)&stats[c0 + q2 * 4];
        float4 q4 = *(const float4*)&stats[256 + c0 + q2 * 4];
        float4 g4 = *(const float4*)&g[c0 + q2 * 4];
        float4 b4 = *(const float4*)&b[c0 + q2 * 4];
        float sm[4] = {s4.x, s4.y, s4.z, s4.w};
        float qm[4] = {q4.x, q4.y, q4.z, q4.w};
        float gm[4] = {g4.x, g4.y, g4.z, g4.w};
        float bm_[4] = {b4.x, b4.y, b4.z, b4.w};
#pragma unroll
        for (int j = 0; j < 4; j++) {
          float m = sm[j] * invN;
          float rs = rsqrtf(qm[j] * invN - m * m + 1e-5f) * gm[j];
          float v = ((float)a8[q2 * 4 + j] - m) * rs + bm_[j];
          v = v > 0.f ? v : 0.f;
          v += (float)r8[q2 * 4 + j];
          o8[q2 * 4 + j] = f2bf(v);
        }
      }
      *(uint4*)&As[(size_t)i * 512 + L * 8] = *(const uint4*)o8;
    }
    __syncthreads();
#pragma unroll
    for (int ks = 0; ks < 2; ks++) {
      s8v af[4], bf[4];
#pragma unroll
      for (int mi = 0; mi < 4; mi++)
        af[mi] = *(const s8v*)&As[(((wm + mi) * 2 + ks) * 64 + L) * 8];
#pragma unroll
      for (int ni = 0; ni < 4; ni++)
        bf[ni] = *(const s8v*)&Bs[(((wn + ni) * 2 + ks) * 64 + L) * 8];
#pragma unroll
      for (int mi = 0; mi < 4; mi++)
#pragma unroll
        for (int ni = 0; ni < 4; ni++)
          acc[mi][ni] = __builtin_amdgcn_mfma_f32_16x16x32_bf16(af[mi], bf[ni], acc[mi][ni], 0, 0, 0);
    }
    __syncthreads();
  }
  // stash acc -> fp16 tile [128][128] overlaying As/Bs
  _Float16* tile = (_Float16*)smem;
#pragma unroll
  for (int ni = 0; ni < 4; ni++) {
    int c = (wn + ni) * 16 + (L & 15);
#pragma unroll
    for (int mi = 0; mi < 4; mi++) {
      int rbase = (wm + mi) * 16 + (L >> 4) * 4;
#pragma unroll
      for (int i = 0; i < 4; i++)
        tile[(rbase + i) * 128 + c] = (_Float16)acc[mi][ni][i];
    }
  }
  __syncthreads();
  // decode: each wave handles 32 consecutive rows
  for (int rr = 0; rr < 32; rr++) {
    int rl = w * 32 + rr;
    int n = bm + rl;
    bool valid = n < N_NODES;
    if (L < 32) {
      float mu = (float)tile[rl * 128 + L] + mub[L];
      float lv = (float)tile[rl * 128 + 32 + L] + lvb[L];
      float zv = 0.f;
      if (valid) {
        out[(size_t)N_NODES * 64 + (size_t)n * 32 + L] = mu;
        out[(size_t)N_NODES * 96 + (size_t)n * 32 + L] = lv;
        zv = mu + eps[(size_t)n * 32 + L] * __expf(0.5f * lv);
      }
      shz[w][L] = zv;
    } else if (L < 62 && valid) {
      int j = L - 32;
      out[(size_t)N_NODES * 128 + (size_t)n * 30 + j] = (float)tile[rl * 128 + 64 + j] + auxb[j];
    }
    __syncthreads();
    float o = decb[L];
#pragma unroll 8
    for (int kk = 0; kk < 32; kk++) o += shz[w][kk] * wsd[kk * 64 + L];
    if (valid) out[(size_t)n * 64 + L] = o;
    __syncthreads();
  }
}

// ---------------------------------------------------------------- aggregate (single pass) + BN partials
#define FMA4(P, B2)                                                                        \
  asm("v_fma_mix_f32 %0, %1, %2, %0 op_sel:[0,0,0] op_sel_hi:[0,1,0]"                      \
      : "+v"(ac0) : "v"(P), "v"((B2).x));                                                  \
  asm("v_fma_mix_f32 %0, %1, %2, %0 op_sel:[0,1,0] op_sel_hi:[0,1,0]"                      \
      : "+v"(ac1) : "v"(P), "v"((B2).x));                                                  \
  asm("v_fma_mix_f32 %0, %1, %2, %0 op_sel:[0,0,0] op_sel_hi:[0,1,0]"                      \
      : "+v"(ac2) : "v"(P), "v"((B2).y));                                                  \
  asm("v_fma_mix_f32 %0, %1, %2, %0 op_sel:[0,1,0] op_sel_hi:[0,1,0]"                      \
      : "+v"(ac3) : "v"(P), "v"((B2).y));

__launch_bounds__(256)
__global__ void k_agg(const int* __restrict__ rowptr, const int* __restrict__ srcs,
                      const float* __restrict__ as_, const float* __restrict__ ad_,
                      const _Float16* __restrict__ B, int ld, const float* __restrict__ gb,
                      _Float16* __restrict__ C, float* __restrict__ part,
                      float* __restrict__ stats) {
  __shared__ float ss[4 * 512];
  int t = threadIdx.x;
  if (blockIdx.x == 0) {  // fold stats zeroing (consumed only after this kernel)
    stats[t] = 0.f; stats[t + 256] = 0.f;
  }
  int w = t >> 6, lane = t & 63;
  int h = lane >> 3;
  int cb = lane << 2;     // 4 channels per lane
  int ldu = ld >> 2;      // row stride in uint2 (8B) units
  const uint2* Bu = (const uint2*)B;
  float4 g4 = *(const float4*)&gb[cb];
  float sts0 = 0.f, sts1 = 0.f, sts2 = 0.f, sts3 = 0.f;
  float stq0 = 0.f, stq1 = 0.f, stq2 = 0.f, stq3 = 0.f;

  for (int n = blockIdx.x * 4 + w; n < N_NODES; n += AGG_WAVES) {
    int beg = rowptr[n], end = rowptr[n + 1];
    float ad_nh = ad_[n * NH + h];
    float ac0 = 0.f, ac1 = 0.f, ac2 = 0.f, ac3 = 0.f, wsum = 0.f;
    int k = beg;
    for (; k + 4 <= end; k += 4) {
      int s0 = srcs[k], s1 = srcs[k + 1], s2 = srcs[k + 2], s3 = srcs[k + 3];
      uint2 b0 = Bu[(size_t)s0 * ldu + lane];
      uint2 b1 = Bu[(size_t)s1 * ldu + lane];
      uint2 b2 = Bu[(size_t)s2 * ldu + lane];
      uint2 b3 = Bu[(size_t)s3 * ldu + lane];
      float e0 = as_[s0 * NH + h] + ad_nh; e0 = e0 > 0.f ? e0 : 0.2f * e0;
      float e1 = as_[s1 * NH + h] + ad_nh; e1 = e1 > 0.f ? e1 : 0.2f * e1;
      float e2 = as_[s2 * NH + h] + ad_nh; e2 = e2 > 0.f ? e2 : 0.2f * e2;
      float e3 = as_[s3 * NH + h] + ad_nh; e3 = e3 > 0.f ? e3 : 0.2f * e3;
      float p0 = __expf(e0), p1 = __expf(e1), p2 = __expf(e2), p3 = __expf(e3);
      wsum += (p0 + p1) + (p2 + p3);
      FMA4(p0, b0)
      FMA4(p1, b1)
      FMA4(p2, b2)
      FMA4(p3, b3)
    }
    for (; k < end; k++) {
      int s = srcs[k];
      h4v b4 = *(const h4v*)&B[(size_t)s * ld + cb];
      float e = as_[s * NH + h] + ad_nh;
      e = e > 0.f ? e : 0.2f * e;
      float p = __expf(e);
      wsum += p;
      ac0 += p * (float)b4[0]; ac1 += p * (float)b4[1];
      ac2 += p * (float)b4[2]; ac3 += p * (float)b4[3];
    }
    float inv = 1.f / (wsum + 1e-16f);
    float v0 = ac0 * inv + g4.x, v1 = ac1 * inv + g4.y;
    float v2 = ac2 * inv + g4.z, v3 = ac3 * inv + g4.w;
    h4v o; o[0] = (_Float16)v0; o[1] = (_Float16)v1; o[2] = (_Float16)v2; o[3] = (_Float16)v3;
    *(h4v*)&C[(size_t)n * 256 + cb] = o;
    sts0 += v0; stq0 += v0 * v0;
    sts1 += v1; stq1 += v1 * v1;
    sts2 += v2; stq2 += v2 * v2;
    sts3 += v3; stq3 += v3 * v3;
  }
  // per-wave LDS slots (no atomics), cross-wave sum, plain store of partials
  float* sw = &ss[w * 512];
  sw[cb + 0] = sts0; sw[cb + 1] = sts1; sw[cb + 2] = sts2; sw[cb + 3] = sts3;
  sw[256 + cb + 0] = stq0; sw[256 + cb + 1] = stq1;
  sw[256 + cb + 2] = stq2; sw[256 + cb + 3] = stq3;
  __syncthreads();
  float p0 = ss[t] + ss[512 + t] + ss[1024 + t] + ss[1536 + t];
  float p1 = ss[256 + t] + ss[768 + t] + ss[1280 + t] + ss[1792 + t];
  part[(size_t)blockIdx.x * 512 + t] = p0;
  part[(size_t)blockIdx.x * 512 + 256 + t] = p1;
}

// reduce AGG_BLOCKS x 512 partials -> stats[512]; 16 blocks, tiny atomic fan-in
__global__ void k_bn_reduce(const float* __restrict__ part, float* __restrict__ stats) {
  int i = threadIdx.x;            // 0..255
  int base = blockIdx.x * (AGG_BLOCKS / 16);
  float s0 = 0.f, s1 = 0.f;
  for (int b = 0; b < AGG_BLOCKS / 16; b++) {
    s0 += part[(size_t)(base + b) * 512 + i];
    s1 += part[(size_t)(base + b) * 512 + 256 + i];
  }
  atomicAdd(&stats[i], s0);
  atomicAdd(&stats[256 + i], s1);
}

// ---------------------------------------------------------------- launch
extern "C" void kernel_launch(void* const* d_in, const int* in_sizes, int n_in,
                              void* d_out, int out_size, void* d_ws, size_t ws_size,
                              hipStream_t stream) {
  (void)in_sizes; (void)n_in; (void)out_size; (void)ws_size;
  const float* x    = (const float*)d_in[0];
  const float* eps  = (const float*)d_in[1];
  const int*   ei   = (const int*)d_in[2];
  const float* gW[3]    = {(const float*)d_in[3],  (const float*)d_in[9],  (const float*)d_in[15]};
  const float* gasrc[3] = {(const float*)d_in[4],  (const float*)d_in[10], (const float*)d_in[16]};
  const float* gadst[3] = {(const float*)d_in[5],  (const float*)d_in[11], (const float*)d_in[17]};
  const float* gbias[3] = {(const float*)d_in[6],  (const float*)d_in[12], (const float*)d_in[18]};
  const float* bng[3]   = {(const float*)d_in[7],  (const float*)d_in[13], (const float*)d_in[19]};
  const float* bnb[3]   = {(const float*)d_in[8],  (const float*)d_in[14], (const float*)d_in[20]};
  const float* resW = (const float*)d_in[21];
  const float* resb = (const float*)d_in[22];
  const float* muW  = (const float*)d_in[23];
  const float* mub  = (const float*)d_in[24];
  const float* lvW  = (const float*)d_in[25];
  const float* lvb  = (const float*)d_in[26];
  const float* decW = (const float*)d_in[27];
  const float* decb = (const float*)d_in[28];
  const float* auxW = (const float*)d_in[29];
  const float* auxb = (const float*)d_in[30];
  float* out = (float*)d_out;

  char* ws = (char*)d_ws;
  size_t off = 0;
  auto alloc = [&](size_t bytes) -> void* {
    void* p = ws + off;
    off += (bytes + 255) & ~(size_t)255;
    return p;
  };
  _Float16* X0R = (_Float16*)alloc((size_t)N_NODES * 512 * 2); // layer1 GEMM out [gat1|residual] (fp16)
  _Float16* X0  = (_Float16*)alloc((size_t)N_NODES * HC * 2);  // layer2/3 GEMM out (fp16)
  _Float16* X1  = (_Float16*)alloc((size_t)N_NODES * HC * 2);  // agg output (fp16)
  ushort* Xb    = (ushort*)alloc((size_t)N_NODES * HC * 2);    // bf16 x (layer-1 input)
  float*  as_   = (float*)alloc((size_t)N_NODES * NH * 4);
  float*  ad_   = (float*)alloc((size_t)N_NODES * NH * 4);
  float*  stats = (float*)alloc(512 * 4);
  float*  part  = (float*)alloc((size_t)AGG_BLOCKS * 512 * 4); // 4 MB BN partials
  int* cnt      = (int*)alloc((size_t)N_NODES * 4);
  int* rowptr   = (int*)alloc((size_t)(N_NODES + 1) * 4);
  int* fillptr  = (int*)alloc((size_t)N_NODES * 4);
  int* srcs     = (int*)alloc((size_t)(N_NODES + N_EDGES) * 4);
  int* bsum     = (int*)alloc(256 * 4);
  ushort* WtP   = (ushort*)alloc(512 * 128 * 2);  // [gat1_Wt ; res_Wt]
  ushort* Wt2   = (ushort*)alloc(256 * 256 * 2);
  ushort* Wt3   = (ushort*)alloc(256 * 256 * 2);
  ushort* Wth   = (ushort*)alloc(128 * 256 * 2);

  const int NB = (N_NODES + 255) / 256;
  // CSR build
  k_init_cnt<<<NB, 256, 0, stream>>>(cnt);
  k_count<<<(N_EDGES + 255) / 256, 256, 0, stream>>>(ei + N_EDGES, cnt);
  k_scan_bsum<<<NB, 256, 0, stream>>>(cnt, bsum);
  k_scan_offsets<<<1, 256, 0, stream>>>(bsum, NB);
  k_scan_write<<<NB, 256, 0, stream>>>(cnt, bsum, rowptr, fillptr);
  k_fill<<<(N_NODES + N_EDGES + 255) / 256, 256, 0, stream>>>(ei, ei + N_EDGES, fillptr, srcs);

  // weight prep (one kernel) + x -> bf16
  k_prep<<<320, 256, 0, stream>>>(gW[0], resW, gW[1], gW[2], muW, lvW, auxW, WtP, Wt2, Wt3, Wth);
  k_cvt_x<<<(N_NODES * 128) / 1024, 256, 0, stream>>>(x, Xb);

  const int GM = (N_NODES + 127) / 128;  // 391

  // layer 1 + residual fused (+ att epilogue on cols 0-255); N=512 -> 8 col-tiles
  k_gemm_bf16<_Float16><<<dim3(GM, 8), 256, 0, stream>>>(
      Xb, WtP, resb, 256, X0R, N_NODES, 128, 512, gasrc[0], gadst[0], as_, ad_);
  k_agg<<<AGG_BLOCKS, 256, 0, stream>>>(rowptr, srcs, as_, ad_, X0R, 512, gbias[0], X1, part, stats);
  k_bn_reduce<<<16, 256, 0, stream>>>(part, stats);

  // layer 2: BN(layer-1 stats) fused into GEMM A-staging (+ att epilogue)
  k_gemm_bn<<<dim3(GM, 4), 256, 0, stream>>>(
      X1, Wt2, stats, bng[0], bnb[0], X0, gasrc[1], gadst[1], as_, ad_);
  k_agg<<<AGG_BLOCKS, 256, 0, stream>>>(rowptr, srcs, as_, ad_, X0, 256, gbias[1], X1, part, stats);
  k_bn_reduce<<<16, 256, 0, stream>>>(part, stats);

  // layer 3: BN(layer-2 stats) fused into GEMM A-staging (+ att epilogue)
  k_gemm_bn<<<dim3(GM, 4), 256, 0, stream>>>(
      X1, Wt3, stats, bng[1], bnb[1], X0, gasrc[2], gadst[2], as_, ad_);
  k_agg<<<AGG_BLOCKS, 256, 0, stream>>>(rowptr, srcs, as_, ad_, X0, 256, gbias[2], X1, part, stats);
  k_bn_reduce<<<16, 256, 0, stream>>>(part, stats);

  // head GEMM: BN(layer-3 stats) + residual fused into A-staging + decode epilogue
  k_gemm_head<<<GM, 256, 0, stream>>>(
      X1, X0R + 256, stats, bng[2], bnb[2], Wth, eps, mub, lvb, auxb, decW, decb, out);
}